// Round 13
// baseline (266.334 us; speedup 1.0000x reference)
//
#include <hip/hip_runtime.h>
#include <hip/hip_bf16.h>
#include <cstdint>

// out = softmax((x@Wq)(cond@Wkv[:,:64])^T / 8) @ (cond@Wkv[:,64:])
// B=4, M=N=4096, DQ=256, H=64. fp32 in/out.
//
// R4: NSP 8, defer-max, permlane transpose, fused proj. 138.2 -> 134.9.
// R5: reg-staged dbuf + Lc-MFMA l-sum: spill regression (143.0). Reverted.
// R6: tree-sum, max3 tree, m_run init 8, setprio. -> 133.2.
// R7/R8: async zero-VGPR global_load_lds staging + XOR swizzle. ~null.
//     (R7 hit the "container failed twice" infra error; R8 byte-identical
//     resubmit passed -> this error class has a confirmed flake instance.)
// R9: proj 32-row blocks; fa acc-seeded -m_run, per-lane guard. -> 131.0.
// R10: XCD sp-swizzle: null; reverted. R11: deferred l + f16 Opart -> 128.4.
// R12: unroll-2 spill catastrophe (159.3). R13: m-ref=0 alone mildly neg
//     (130.5). R14: R11 restored -> 129.7 (plateau confirmed, noise band).
// R15: fused split-K merge (last-arriving block merges): container failed
//     twice (same opaque infra error as R7). Audit found no hang path (no
//     spins; counters reset by wtrans under graph replay; bounds exact) but
//     DID find a soft defect: no acquire fence on the reader side of the
//     atomic handshake (relaxed atomicAdd -> cross-XCD visibility of
//     partials not guaranteed; G16).
// R16 (this round): R15 + reader-side __threadfence() (acquire pairing to
//     the writer's release fence). One retry for the flake class; if it
//     fails identically again, revert to R14 as final.

#define BB 4
#define MM 4096
#define NN 4096
#define DQm 256
#define DH 64
#define NSP 8                        // KV splits
#define NITER (NN / 64 / NSP)        // fa inner iterations per block (8)
#define QSCALE 0.18033688011112042f  // log2(e)/8

typedef _Float16 half8 __attribute__((ext_vector_type(8)));
typedef _Float16 half4 __attribute__((ext_vector_type(4)));
typedef float floatx16 __attribute__((ext_vector_type(16)));

static __device__ __forceinline__ unsigned pkrtz(float a, float b) {
    union { __fp16 h __attribute__((ext_vector_type(2))); unsigned u; } cv;
    cv.h = __builtin_amdgcn_cvt_pkrtz(a, b);
    return cv.u;
}

static __device__ __forceinline__ void gload16(const void* g, void* l) {
    __builtin_amdgcn_global_load_lds(
        (const __attribute__((address_space(1))) void*)g,
        (__attribute__((address_space(3))) void*)l, 16, 0, 0);
}

// ---------------- W transpose + f16 hi/lo split (+ counter reset) -----------
__global__ __launch_bounds__(256) void wtrans_kernel(const float* __restrict__ Wq,
                                                     const float* __restrict__ Wkv,
                                                     _Float16* __restrict__ wt,
                                                     unsigned* __restrict__ cnt) {
    int cout = blockIdx.x;   // 0..191 : 0-63 q (scaled), 64-127 k, 128-191 v
    int t = threadIdx.x;     // k index 0..255
    if (cout == 0 && t < BB * 32) cnt[t] = 0;   // split-K fixup counters
    float v = (cout < 64) ? Wq[t * 64 + cout] * QSCALE : Wkv[t * 128 + (cout - 64)];
    _Float16 hi = (_Float16)v;
    _Float16 lo = (_Float16)(v - (float)hi);
    wt[cout * DQm + t] = hi;
    wt[192 * DQm + cout * DQm + t] = lo;
}

// ---------------- fused Q + KV projection: 32 rows/block --------------------
__global__ __launch_bounds__(256) void proj_kernel(const float* __restrict__ x,
                                                   const float* __restrict__ cond,
                                                   const _Float16* __restrict__ wt,
                                                   _Float16* __restrict__ q_h,
                                                   _Float16* __restrict__ k_h,
                                                   _Float16* __restrict__ vt_h) {
    __shared__ __align__(16) _Float16 xh[32][264];
    __shared__ __align__(16) _Float16 xl[32][264];
    const int t = threadIdx.x;
    const bool isq = blockIdx.x < (BB * MM / 32);
    const int blk = isq ? blockIdx.x : blockIdx.x - BB * MM / 32;
    const long row0 = (long)blk * 32;
    const float4* xg = (const float4*)((isq ? x : cond) + row0 * DQm);
#pragma unroll
    for (int it = 0; it < 8; ++it) {
        int fid = t + it * 256;
        int row = fid >> 6, c4 = fid & 63;
        float4 v = xg[fid];
        half4 hh = {(_Float16)v.x, (_Float16)v.y, (_Float16)v.z, (_Float16)v.w};
        half4 hl = {(_Float16)(v.x - (float)hh[0]), (_Float16)(v.y - (float)hh[1]),
                    (_Float16)(v.z - (float)hh[2]), (_Float16)(v.w - (float)hh[3])};
        *(half4*)(&xh[row][c4 * 4]) = hh;
        *(half4*)(&xl[row][c4 * 4]) = hl;
    }
    __syncthreads();
    const int lane = t & 63, w = t >> 6, c = lane & 31, h = lane >> 5;
    const _Float16* wlo = wt + 192 * DQm;

    if (isq) {
        const int kh = w & 1, ct = w >> 1;   // kt half x col tile
        floatx16 a1, a2, a3;
#pragma unroll
        for (int i = 0; i < 16; ++i) { a1[i] = 0.f; a2[i] = 0.f; a3[i] = 0.f; }
#pragma unroll
        for (int k8 = 0; k8 < 8; ++k8) {
            int kt = kh * 8 + k8;
            half8 ah = *(const half8*)(&xh[c][kt * 16 + h * 8]);
            half8 al = *(const half8*)(&xl[c][kt * 16 + h * 8]);
            half8 bh = *(const half8*)(wt  + (long)(ct * 32 + c) * DQm + kt * 16 + h * 8);
            half8 bl = *(const half8*)(wlo + (long)(ct * 32 + c) * DQm + kt * 16 + h * 8);
            a1 = __builtin_amdgcn_mfma_f32_32x32x16_f16(ah, bh, a1, 0, 0, 0);
            a2 = __builtin_amdgcn_mfma_f32_32x32x16_f16(ah, bl, a2, 0, 0, 0);
            a3 = __builtin_amdgcn_mfma_f32_32x32x16_f16(al, bh, a3, 0, 0, 0);
        }
        float s[16];
#pragma unroll
        for (int i = 0; i < 16; ++i) s[i] = a1[i] + a2[i] + a3[i];
        // pair-reduce kh=1 -> kh=0 via LDS (reuse xh space; f32 view)
        float* red = (float*)&xh[0][0];   // 2 ct x 16 i x 64 lanes f32 = 8KB
        __syncthreads();                  // all waves done reading xh/xl
        if (kh == 1) {
#pragma unroll
            for (int i = 0; i < 16; ++i) red[ct * 1024 + i * 64 + lane] = s[i];
        }
        __syncthreads();
        if (kh == 0) {
#pragma unroll
            for (int i = 0; i < 16; ++i) s[i] += red[ct * 1024 + i * 64 + lane];
#pragma unroll
            for (int r = 0; r < 16; ++r) {
                int m = (r & 3) + 8 * (r >> 2) + 4 * h;
                q_h[(row0 + m) * DH + ct * 32 + c] = (_Float16)s[r];
            }
        }
    } else {
        const int ct = w;                    // 4 col tiles over 128 couts
        floatx16 a1, a2, a3;
#pragma unroll
        for (int i = 0; i < 16; ++i) { a1[i] = 0.f; a2[i] = 0.f; a3[i] = 0.f; }
        const long wrow = 64 + ct * 32 + c;
#pragma unroll
        for (int kt = 0; kt < 16; ++kt) {
            half8 ah = *(const half8*)(&xh[c][kt * 16 + h * 8]);
            half8 al = *(const half8*)(&xl[c][kt * 16 + h * 8]);
            half8 bh = *(const half8*)(wt  + wrow * DQm + kt * 16 + h * 8);
            half8 bl = *(const half8*)(wlo + wrow * DQm + kt * 16 + h * 8);
            a1 = __builtin_amdgcn_mfma_f32_32x32x16_f16(ah, bh, a1, 0, 0, 0);
            a2 = __builtin_amdgcn_mfma_f32_32x32x16_f16(ah, bl, a2, 0, 0, 0);
            a3 = __builtin_amdgcn_mfma_f32_32x32x16_f16(al, bh, a3, 0, 0, 0);
        }
        int cout = ct * 32 + c;              // 0..127 within kv range
        if (cout < 64) {
#pragma unroll
            for (int r = 0; r < 16; ++r) {
                int m = (r & 3) + 8 * (r >> 2) + 4 * h;
                k_h[(row0 + m) * DH + cout] = (_Float16)(a1[r] + a2[r] + a3[r]);
            }
        } else {
            int d = cout - 64;
            long bb = row0 >> 12;  // batch (blocks never straddle)
#pragma unroll
            for (int s2 = 0; s2 < 4; ++s2) {
                long n = row0 + 8 * s2 + 4 * h;
                half4 hv;
#pragma unroll
                for (int j = 0; j < 4; ++j)
                    hv[j] = (_Float16)(a1[s2 * 4 + j] + a2[s2 * 4 + j] +
                                       a3[s2 * 4 + j]);
                *(half4*)(vt_h + (bb * DH + d) * NN + (n & 4095)) = hv;
            }
        }
    }
}

// ---------------- Flash attention + fused split-K merge ---------------------
// grid 1024 = sp(8) x b(4) x mtile(32), ALL co-resident (4 blocks/CU).
// Main loop identical to R11 (measured best). Epilogue: store f16 partial,
// __threadfence (release) + atomicAdd; last split of (b,mt) does acquire
// __threadfence then merges in-kernel.
__global__ __launch_bounds__(256, 4) void fa_kernel(const _Float16* __restrict__ q_h,
                                                    const _Float16* __restrict__ k_h,
                                                    const _Float16* __restrict__ vt_h,
                                                    _Float16* __restrict__ Opart,
                                                    float2* __restrict__ ml,
                                                    unsigned* __restrict__ cnt,
                                                    float* __restrict__ out) {
    __shared__ __align__(16) _Float16 k_lds[2][64][64];   // [n][d], swizzled
    __shared__ __align__(16) _Float16 vt_lds[2][64][64];  // [d][n], swizzled

    const int t = threadIdx.x;
    const int w = t >> 6;
    const int lane = t & 63;
    const int c = lane & 31;   // MFMA col == this lane's Q row (local)
    const int h = lane >> 5;

    const int bid = blockIdx.x;
    const int sp = bid >> 7;          // KV split 0..7 (R9 decode, measured best)
    const int b  = (bid >> 5) & 3;
    const int mt = bid & 31;
    const int mbase = mt * 128 + w * 32;
    const long qrow = (long)b * MM + mbase + c;

    // ---- staging geometry: 4 gload16/thread/iter (K:2, V:2) ----
    // dest byte p in the 8KB tile; LDS holds tile[SWZ(p)], SWZ(p)=p^(((p>>7)&7)<<4)
    const int p0 = w * 2048 + (lane << 4);
    const int p1 = p0 + 1024;
    const int q0 = p0 ^ (((p0 >> 7) & 7) << 4);   // SWZ(p0)
    const int q1 = p1 ^ (((p1 >> 7) & 7) << 4);
    const int n0f = sp * NITER * 64;              // first n0 of this split
    const char* ks0 = (const char*)k_h + ((long)b * NN + n0f) * DH * 2 + q0;
    const char* ks1 = (const char*)k_h + ((long)b * NN + n0f) * DH * 2 + q1;
    const char* vs0 = (const char*)vt_h +
                      (((long)b * DH + (p0 >> 7)) * NN + n0f) * 2 + (q0 & 127);
    const char* vs1 = (const char*)vt_h +
                      (((long)b * DH + (p1 >> 7)) * NN + n0f) * 2 + (q1 & 127);

#define STAGE(bufi)                                                   \
    do {                                                              \
        char* kld = (char*)(&k_lds[bufi][0][0]) + w * 2048;           \
        char* vld = (char*)(&vt_lds[bufi][0][0]) + w * 2048;          \
        gload16(ks0, kld);                                            \
        gload16(ks1, kld + 1024);                                     \
        gload16(vs0, vld);                                            \
        gload16(vs1, vld + 1024);                                     \
        ks0 += 64 * DH * 2; ks1 += 64 * DH * 2;                       \
        vs0 += 128; vs1 += 128;                                       \
    } while (0)

    // read-side swizzle: row*128 + ((col_byte) ^ ((row&7)<<4)); row&7 == c&7
    const int swb = (c & 7) << 4;
    int koff[4];
#pragma unroll
    for (int kt = 0; kt < 4; ++kt) koff[kt] = (kt * 32 + h * 16) ^ swb;

    // Q as B-operand frags (regs all kernel): B[k=d][col=m]
    half8 qf[4];
#pragma unroll
    for (int kt = 0; kt < 4; ++kt)
        qf[kt] = *(const half8*)(q_h + qrow * DH + kt * 16 + h * 8);

    floatx16 Oc0, Oc1;   // O^T accum: d rows (2 tiles of 32), col m=c
#pragma unroll
    for (int i = 0; i < 16; ++i) { Oc0[i] = 0.f; Oc1[i] = 0.f; }
    float l4[4] = {0.f, 0.f, 0.f, 0.f};   // deferred l partials (this lane's half)
    // m_run init 8: on this data the log2-domain row max never nears 16, so
    // the defer-max branch never fires -> no rescale passes at all.
    float m_run = 8.0f;

    STAGE(0);
    __syncthreads();   // compiler drains vmcnt(0) before barrier

#pragma unroll 1
    for (int it = 0; it < NITER; ++it) {
        const int pb = it & 1;
        if (it + 1 < NITER) STAGE(pb ^ 1);   // prefetch next tile (async)

        const char* kbase = (const char*)(&k_lds[pb][0][0]);
        const char* vbase = (const char*)(&vt_lds[pb][0][0]);

        // S^T - m_run = K * Q^T + (-m_run): acc seeded with -m_run so the
        // softmax subtract comes free out of the MFMA.
        floatx16 Sc[2];
        const float negm = -m_run;
        __builtin_amdgcn_s_setprio(1);
#pragma unroll
        for (int a = 0; a < 2; ++a) {
            floatx16 acc;
#pragma unroll
            for (int i = 0; i < 16; ++i) acc[i] = negm;
#pragma unroll
            for (int kt = 0; kt < 4; ++kt) {
                half8 af = *(const half8*)(kbase + (a * 32 + c) * 128 + koff[kt]);
                acc = __builtin_amdgcn_mfma_f32_32x32x16_f16(af, qf[kt], acc, 0, 0, 0);
            }
            Sc[a] = acc;
        }
        __builtin_amdgcn_s_setprio(0);

        // guard: per-lane max3 tree over Sc (no cross-lane shfl on fast path)
        float t3[11];
#pragma unroll
        for (int i = 0; i < 10; ++i) {
            float u0 = (3 * i < 16) ? Sc[0][3 * i] : Sc[1][3 * i - 16];
            float u1 = (3 * i + 1 < 16) ? Sc[0][3 * i + 1] : Sc[1][3 * i - 15];
            float u2 = (3 * i + 2 < 16) ? Sc[0][3 * i + 2] : Sc[1][3 * i - 14];
            t3[i] = fmaxf(fmaxf(u0, u1), u2);
        }
        t3[10] = fmaxf(Sc[1][14], Sc[1][15]);
        float m0 = fmaxf(fmaxf(t3[0], t3[1]), t3[2]);
        float m1 = fmaxf(fmaxf(t3[3], t3[4]), t3[5]);
        float m2 = fmaxf(fmaxf(t3[6], t3[7]), t3[8]);
        float lmax = fmaxf(fmaxf(m0, m1), fmaxf(m2, fmaxf(t3[9], t3[10])));
        if (__any(lmax > 8.0f)) {   // never on this data
            float tt = fmaxf(lmax, __shfl_xor(lmax, 32, 64));  // exact row max
            float alpha = exp2f(-tt);
#pragma unroll
            for (int j = 0; j < 4; ++j) l4[j] *= alpha;
#pragma unroll
            for (int i = 0; i < 16; ++i) { Oc0[i] *= alpha; Oc1[i] *= alpha; }
#pragma unroll
            for (int a = 0; a < 2; ++a)
#pragma unroll
                for (int r = 0; r < 16; ++r) Sc[a][r] -= tt;
            m_run += tt;
        }
#pragma unroll
        for (int a = 0; a < 2; ++a)
#pragma unroll
            for (int r = 0; r < 16; ++r) Sc[a][r] = exp2f(Sc[a][r]);

        // P: C-layout -> B-operand frags, in-register.
#pragma unroll
        for (int a = 0; a < 2; ++a) {
            uint2 pk0 = {pkrtz(Sc[a][0],  Sc[a][1]),  pkrtz(Sc[a][2],  Sc[a][3])};
            uint2 pk1 = {pkrtz(Sc[a][4],  Sc[a][5]),  pkrtz(Sc[a][6],  Sc[a][7])};
            uint2 pk2 = {pkrtz(Sc[a][8],  Sc[a][9]),  pkrtz(Sc[a][10], Sc[a][11])};
            uint2 pk3 = {pkrtz(Sc[a][12], Sc[a][13]), pkrtz(Sc[a][14], Sc[a][15])};
            union { uint4 u; half8 f; } f0, f1;
#if __has_builtin(__builtin_amdgcn_permlane32_swap)
            {
                auto r0s = __builtin_amdgcn_permlane32_swap(pk0.x, pk1.x, false, false);
                auto r1s = __builtin_amdgcn_permlane32_swap(pk0.y, pk1.y, false, false);
                auto r2s = __builtin_amdgcn_permlane32_swap(pk2.x, pk3.x, false, false);
                auto r3s = __builtin_amdgcn_permlane32_swap(pk2.y, pk3.y, false, false);
                f0.u.x = r0s[0]; f0.u.z = r0s[1];
                f0.u.y = r1s[0]; f0.u.w = r1s[1];
                f1.u.x = r2s[0]; f1.u.z = r2s[1];
                f1.u.y = r3s[0]; f1.u.w = r3s[1];
            }
#else
            {
                uint2 s0, s1, ex0, ex1;
                s0.x = h ? pk0.x : pk1.x;  s0.y = h ? pk0.y : pk1.y;
                s1.x = h ? pk2.x : pk3.x;  s1.y = h ? pk2.y : pk3.y;
                ex0.x = __shfl_xor((int)s0.x, 32, 64);
                ex0.y = __shfl_xor((int)s0.y, 32, 64);
                ex1.x = __shfl_xor((int)s1.x, 32, 64);
                ex1.y = __shfl_xor((int)s1.y, 32, 64);
                f0.u.x = h ? ex0.x : pk0.x;  f0.u.y = h ? ex0.y : pk0.y;
                f0.u.z = h ? pk1.x : ex0.x;  f0.u.w = h ? pk1.y : ex0.y;
                f1.u.x = h ? ex1.x : pk2.x;  f1.u.y = h ? ex1.y : pk2.y;
                f1.u.z = h ? pk3.x : ex1.x;  f1.u.w = h ? pk3.y : ex1.y;
            }
#endif
            // O^T += V^T * P^T for kt = 2a, 2a+1
            __builtin_amdgcn_s_setprio(1);
#pragma unroll
            for (int bq = 0; bq < 2; ++bq) {
                int kt = 2 * a + bq;
                half8 pf = bq ? f1.f : f0.f;
                half8 vf0 = *(const half8*)(vbase + c * 128 + koff[kt]);
                half8 vf1 = *(const half8*)(vbase + (32 + c) * 128 + koff[kt]);
                Oc0 = __builtin_amdgcn_mfma_f32_32x32x16_f16(vf0, pf, Oc0, 0, 0, 0);
                Oc1 = __builtin_amdgcn_mfma_f32_32x32x16_f16(vf1, pf, Oc1, 0, 0, 0);
            }
            __builtin_amdgcn_s_setprio(0);
        }

        // deferred l accumulation: AFTER PV issue (off the critical path),
        // tree to 4 per-lane partials, no cross-lane op.
        {
            float t16v[8];
#pragma unroll
            for (int i = 0; i < 8; ++i)
                t16v[i] = (Sc[0][i] + Sc[0][i + 8]) + (Sc[1][i] + Sc[1][i + 8]);
#pragma unroll
            for (int j = 0; j < 4; ++j) l4[j] += t16v[j] + t16v[j + 4];
        }

        __syncthreads();   // drains vmcnt -> prefetched tile ready; LDS reuse safe
    }
#undef STAGE

    // epilogue: finish l, normalize, store f16 partial + (m,l)
    float lsum = (l4[0] + l4[1]) + (l4[2] + l4[3]);
    lsum += __shfl_xor(lsum, 32, 64);
    const float inv = 1.0f / lsum;
    const long obase = ((long)sp * BB * MM + (long)b * MM + mbase + c) * DH;
#pragma unroll
    for (int dt = 0; dt < 2; ++dt) {
        const floatx16& O = dt ? Oc1 : Oc0;
#pragma unroll
        for (int s2 = 0; s2 < 4; ++s2) {
            uint2 hv;
            hv.x = pkrtz(O[s2 * 4 + 0] * inv, O[s2 * 4 + 1] * inv);
            hv.y = pkrtz(O[s2 * 4 + 2] * inv, O[s2 * 4 + 3] * inv);
            *(uint2*)(Opart + obase + dt * 32 + s2 * 8 + h * 4) = hv;
        }
    }
    if (h == 0)
        ml[((long)sp * BB + b) * MM + mbase + c] = make_float2(m_run, lsum);

    // ---- fused split-K merge: last-arriving split of (b,mt) merges --------
    __threadfence();   // release: partials visible device-wide before count
    __shared__ unsigned last;
    if (t == 0) last = atomicAdd(&cnt[b * 32 + mt], 1u);
    __syncthreads();
    if (last == NSP - 1) {
        __threadfence();   // acquire: other splits' partials visible to reads
        const long rowbase = (long)mt * 128;
#pragma unroll
        for (int cc = 0; cc < 4; ++cc) {
            int chunk = t + cc * 256;            // 0..1023 (128 rows x 8 chunks)
            int row_l = chunk >> 3;
            long row = rowbase + row_l;          // m row within batch
            float2 p[NSP];
            float mmax = -INFINITY;
#pragma unroll
            for (int i = 0; i < NSP; ++i) {
                p[i] = ml[((long)i * BB + b) * MM + row];
                mmax = fmaxf(mmax, p[i].x);
            }
            float denom = 0.f;
            float o[8] = {0.f, 0.f, 0.f, 0.f, 0.f, 0.f, 0.f, 0.f};
            long g8 = ((long)b * MM + row) * 8 + (chunk & 7);  // 8-chunk index
#pragma unroll
            for (int i = 0; i < NSP; ++i) {
                float wi = exp2f(p[i].x - mmax) * p[i].y;
                denom += wi;
                half8 v = *(const half8*)(Opart + (long)i * (BB * MM * DH) + g8 * 8);
#pragma unroll
                for (int j = 0; j < 8; ++j) o[j] += wi * (float)v[j];
            }
            float invd = 1.0f / denom;
            float4 o0 = {o[0] * invd, o[1] * invd, o[2] * invd, o[3] * invd};
            float4 o1 = {o[4] * invd, o[5] * invd, o[6] * invd, o[7] * invd};
            ((float4*)out)[g8 * 2] = o0;
            ((float4*)out)[g8 * 2 + 1] = o1;
        }
    }
}

extern "C" void kernel_launch(void* const* d_in, const int* in_sizes, int n_in,
                              void* d_out, int out_size, void* d_ws, size_t ws_size,
                              hipStream_t stream) {
    const float* x    = (const float*)d_in[0];
    const float* cond = (const float*)d_in[1];
    const float* Wq   = (const float*)d_in[2];
    const float* Wkv  = (const float*)d_in[3];
    float* out = (float*)d_out;

    char* ws = (char*)d_ws;
    // ws: wt 192KB | q 2MB | k 2MB | vt 2MB | Opart(f16) 8x2MB | ml 1MB |
    //     cnt 512B   ~ 23.2MB
    _Float16* wt   = (_Float16*)(ws);
    _Float16* q_h  = (_Float16*)(ws + 196608);
    _Float16* k_h  = (_Float16*)(ws + 196608 + 2097152);
    _Float16* vt_h = (_Float16*)(ws + 196608 + 2 * 2097152);
    _Float16* Op   = (_Float16*)(ws + 196608 + 3 * 2097152);
    float2*   mlp  = (float2*)(ws + 196608 + 3 * 2097152 + (size_t)NSP * 2097152);
    unsigned* cnt  = (unsigned*)(ws + 196608 + 3 * 2097152 +
                                 (size_t)NSP * 2097152 + 1048576);

    wtrans_kernel<<<192, 256, 0, stream>>>(Wq, Wkv, wt, cnt);
    proj_kernel<<<BB * (MM + NN) / 32, 256, 0, stream>>>(x, cond, wt, q_h, k_h, vt_h);
    fa_kernel<<<NSP * BB * 32, 256, 0, stream>>>(q_h, k_h, vt_h, Op, mlp, cnt, out);
}

// Round 14
// 127.518 us; speedup vs baseline: 2.0886x; 2.0886x over previous
//
#include <hip/hip_runtime.h>
#include <hip/hip_bf16.h>
#include <cstdint>

// out = softmax((x@Wq)(cond@Wkv[:,:64])^T / 8) @ (cond@Wkv[:,64:])
// B=4, M=N=4096, DQ=256, H=64. fp32 in/out.
//
// R4: NSP 8, defer-max, permlane transpose, fused proj. 138.2 -> 134.9.
// R5: reg-staged dbuf + Lc-MFMA l-sum: spill regression (143.0). Reverted.
// R6: tree-sum, max3 tree, m_run init 8, setprio. -> 133.2.
// R7/R8: async zero-VGPR global_load_lds staging + XOR swizzle. ~null.
// R9: proj 32-row blocks; fa acc-seeded -m_run, per-lane guard. -> 131.0.
// R10: XCD sp-swizzle: null; reverted. R11: deferred l + f16 Opart -> 128.4
//     (BEST; reconfirmed 129.7 in R14).
// R12: unroll-2 spill catastrophe (159.3). R13: m-ref=0 alone mildly neg.
// R15/R16: fused split-K merge: infra-fail, then 266us — merge epilogue's
//     register demand spilled MAIN-LOOP state under the 128-VGPR cap
//     (SGPR 112, bank-conflict counter saturated at 2^21, MfmaUtil 3.6%).
//     Third confirmation: fa has ZERO register headroom; nothing may be
//     appended to the kernel body. Fused-merge line abandoned.
// R17 (final): R11 verbatim — the measured best configuration.

#define BB 4
#define MM 4096
#define NN 4096
#define DQm 256
#define DH 64
#define NSP 8                        // KV splits
#define NITER (NN / 64 / NSP)        // fa inner iterations per block (8)
#define QSCALE 0.18033688011112042f  // log2(e)/8

typedef _Float16 half8 __attribute__((ext_vector_type(8)));
typedef _Float16 half4 __attribute__((ext_vector_type(4)));
typedef float floatx16 __attribute__((ext_vector_type(16)));

static __device__ __forceinline__ unsigned pkrtz(float a, float b) {
    union { __fp16 h __attribute__((ext_vector_type(2))); unsigned u; } cv;
    cv.h = __builtin_amdgcn_cvt_pkrtz(a, b);
    return cv.u;
}

static __device__ __forceinline__ void gload16(const void* g, void* l) {
    __builtin_amdgcn_global_load_lds(
        (const __attribute__((address_space(1))) void*)g,
        (__attribute__((address_space(3))) void*)l, 16, 0, 0);
}

// ---------------- W transpose + f16 hi/lo split -----------------------------
__global__ __launch_bounds__(256) void wtrans_kernel(const float* __restrict__ Wq,
                                                     const float* __restrict__ Wkv,
                                                     _Float16* __restrict__ wt) {
    int cout = blockIdx.x;   // 0..191 : 0-63 q (scaled), 64-127 k, 128-191 v
    int t = threadIdx.x;     // k index 0..255
    float v = (cout < 64) ? Wq[t * 64 + cout] * QSCALE : Wkv[t * 128 + (cout - 64)];
    _Float16 hi = (_Float16)v;
    _Float16 lo = (_Float16)(v - (float)hi);
    wt[cout * DQm + t] = hi;
    wt[192 * DQm + cout * DQm + t] = lo;
}

// ---------------- fused Q + KV projection: 32 rows/block --------------------
__global__ __launch_bounds__(256) void proj_kernel(const float* __restrict__ x,
                                                   const float* __restrict__ cond,
                                                   const _Float16* __restrict__ wt,
                                                   _Float16* __restrict__ q_h,
                                                   _Float16* __restrict__ k_h,
                                                   _Float16* __restrict__ vt_h) {
    __shared__ __align__(16) _Float16 xh[32][264];
    __shared__ __align__(16) _Float16 xl[32][264];
    const int t = threadIdx.x;
    const bool isq = blockIdx.x < (BB * MM / 32);
    const int blk = isq ? blockIdx.x : blockIdx.x - BB * MM / 32;
    const long row0 = (long)blk * 32;
    const float4* xg = (const float4*)((isq ? x : cond) + row0 * DQm);
#pragma unroll
    for (int it = 0; it < 8; ++it) {
        int fid = t + it * 256;
        int row = fid >> 6, c4 = fid & 63;
        float4 v = xg[fid];
        half4 hh = {(_Float16)v.x, (_Float16)v.y, (_Float16)v.z, (_Float16)v.w};
        half4 hl = {(_Float16)(v.x - (float)hh[0]), (_Float16)(v.y - (float)hh[1]),
                    (_Float16)(v.z - (float)hh[2]), (_Float16)(v.w - (float)hh[3])};
        *(half4*)(&xh[row][c4 * 4]) = hh;
        *(half4*)(&xl[row][c4 * 4]) = hl;
    }
    __syncthreads();
    const int lane = t & 63, w = t >> 6, c = lane & 31, h = lane >> 5;
    const _Float16* wlo = wt + 192 * DQm;

    if (isq) {
        const int kh = w & 1, ct = w >> 1;   // kt half x col tile
        floatx16 a1, a2, a3;
#pragma unroll
        for (int i = 0; i < 16; ++i) { a1[i] = 0.f; a2[i] = 0.f; a3[i] = 0.f; }
#pragma unroll
        for (int k8 = 0; k8 < 8; ++k8) {
            int kt = kh * 8 + k8;
            half8 ah = *(const half8*)(&xh[c][kt * 16 + h * 8]);
            half8 al = *(const half8*)(&xl[c][kt * 16 + h * 8]);
            half8 bh = *(const half8*)(wt  + (long)(ct * 32 + c) * DQm + kt * 16 + h * 8);
            half8 bl = *(const half8*)(wlo + (long)(ct * 32 + c) * DQm + kt * 16 + h * 8);
            a1 = __builtin_amdgcn_mfma_f32_32x32x16_f16(ah, bh, a1, 0, 0, 0);
            a2 = __builtin_amdgcn_mfma_f32_32x32x16_f16(ah, bl, a2, 0, 0, 0);
            a3 = __builtin_amdgcn_mfma_f32_32x32x16_f16(al, bh, a3, 0, 0, 0);
        }
        float s[16];
#pragma unroll
        for (int i = 0; i < 16; ++i) s[i] = a1[i] + a2[i] + a3[i];
        // pair-reduce kh=1 -> kh=0 via LDS (reuse xh space; f32 view)
        float* red = (float*)&xh[0][0];   // 2 ct x 16 i x 64 lanes f32 = 8KB
        __syncthreads();                  // all waves done reading xh/xl
        if (kh == 1) {
#pragma unroll
            for (int i = 0; i < 16; ++i) red[ct * 1024 + i * 64 + lane] = s[i];
        }
        __syncthreads();
        if (kh == 0) {
#pragma unroll
            for (int i = 0; i < 16; ++i) s[i] += red[ct * 1024 + i * 64 + lane];
#pragma unroll
            for (int r = 0; r < 16; ++r) {
                int m = (r & 3) + 8 * (r >> 2) + 4 * h;
                q_h[(row0 + m) * DH + ct * 32 + c] = (_Float16)s[r];
            }
        }
    } else {
        const int ct = w;                    // 4 col tiles over 128 couts
        floatx16 a1, a2, a3;
#pragma unroll
        for (int i = 0; i < 16; ++i) { a1[i] = 0.f; a2[i] = 0.f; a3[i] = 0.f; }
        const long wrow = 64 + ct * 32 + c;
#pragma unroll
        for (int kt = 0; kt < 16; ++kt) {
            half8 ah = *(const half8*)(&xh[c][kt * 16 + h * 8]);
            half8 al = *(const half8*)(&xl[c][kt * 16 + h * 8]);
            half8 bh = *(const half8*)(wt  + wrow * DQm + kt * 16 + h * 8);
            half8 bl = *(const half8*)(wlo + wrow * DQm + kt * 16 + h * 8);
            a1 = __builtin_amdgcn_mfma_f32_32x32x16_f16(ah, bh, a1, 0, 0, 0);
            a2 = __builtin_amdgcn_mfma_f32_32x32x16_f16(ah, bl, a2, 0, 0, 0);
            a3 = __builtin_amdgcn_mfma_f32_32x32x16_f16(al, bh, a3, 0, 0, 0);
        }
        int cout = ct * 32 + c;              // 0..127 within kv range
        if (cout < 64) {
#pragma unroll
            for (int r = 0; r < 16; ++r) {
                int m = (r & 3) + 8 * (r >> 2) + 4 * h;
                k_h[(row0 + m) * DH + cout] = (_Float16)(a1[r] + a2[r] + a3[r]);
            }
        } else {
            int d = cout - 64;
            long bb = row0 >> 12;  // batch (blocks never straddle)
#pragma unroll
            for (int s2 = 0; s2 < 4; ++s2) {
                long n = row0 + 8 * s2 + 4 * h;
                half4 hv;
#pragma unroll
                for (int j = 0; j < 4; ++j)
                    hv[j] = (_Float16)(a1[s2 * 4 + j] + a2[s2 * 4 + j] +
                                       a3[s2 * 4 + j]);
                *(half4*)(vt_h + (bb * DH + d) * NN + (n & 4095)) = hv;
            }
        }
    }
}

// ---------------- Flash attention ------------------------------------------
// grid 1024 = sp(8) x b(4) x mtile(32). 256 thr = 4 waves x 32 Q rows.
// Async 2-phase global_load_lds prefetch, 1 barrier/iter, XOR swizzle
// both-sides. l deferred to epilogue; output normalized f16.
__global__ __launch_bounds__(256, 4) void fa_kernel(const _Float16* __restrict__ q_h,
                                                    const _Float16* __restrict__ k_h,
                                                    const _Float16* __restrict__ vt_h,
                                                    _Float16* __restrict__ Opart,
                                                    float2* __restrict__ ml) {
    __shared__ __align__(16) _Float16 k_lds[2][64][64];   // [n][d], swizzled
    __shared__ __align__(16) _Float16 vt_lds[2][64][64];  // [d][n], swizzled

    const int t = threadIdx.x;
    const int w = t >> 6;
    const int lane = t & 63;
    const int c = lane & 31;   // MFMA col == this lane's Q row (local)
    const int h = lane >> 5;

    const int bid = blockIdx.x;
    const int sp = bid >> 7;          // KV split 0..7 (R9 decode, measured best)
    const int b  = (bid >> 5) & 3;
    const int mt = bid & 31;
    const int mbase = mt * 128 + w * 32;
    const long qrow = (long)b * MM + mbase + c;

    // ---- staging geometry: 4 gload16/thread/iter (K:2, V:2) ----
    // dest byte p in the 8KB tile; LDS holds tile[SWZ(p)], SWZ(p)=p^(((p>>7)&7)<<4)
    const int p0 = w * 2048 + (lane << 4);
    const int p1 = p0 + 1024;
    const int q0 = p0 ^ (((p0 >> 7) & 7) << 4);   // SWZ(p0)
    const int q1 = p1 ^ (((p1 >> 7) & 7) << 4);
    const int n0f = sp * NITER * 64;              // first n0 of this split
    const char* ks0 = (const char*)k_h + ((long)b * NN + n0f) * DH * 2 + q0;
    const char* ks1 = (const char*)k_h + ((long)b * NN + n0f) * DH * 2 + q1;
    const char* vs0 = (const char*)vt_h +
                      (((long)b * DH + (p0 >> 7)) * NN + n0f) * 2 + (q0 & 127);
    const char* vs1 = (const char*)vt_h +
                      (((long)b * DH + (p1 >> 7)) * NN + n0f) * 2 + (q1 & 127);

#define STAGE(bufi)                                                   \
    do {                                                              \
        char* kld = (char*)(&k_lds[bufi][0][0]) + w * 2048;           \
        char* vld = (char*)(&vt_lds[bufi][0][0]) + w * 2048;          \
        gload16(ks0, kld);                                            \
        gload16(ks1, kld + 1024);                                     \
        gload16(vs0, vld);                                            \
        gload16(vs1, vld + 1024);                                     \
        ks0 += 64 * DH * 2; ks1 += 64 * DH * 2;                       \
        vs0 += 128; vs1 += 128;                                       \
    } while (0)

    // read-side swizzle: row*128 + ((col_byte) ^ ((row&7)<<4)); row&7 == c&7
    const int swb = (c & 7) << 4;
    int koff[4];
#pragma unroll
    for (int kt = 0; kt < 4; ++kt) koff[kt] = (kt * 32 + h * 16) ^ swb;

    // Q as B-operand frags (regs all kernel): B[k=d][col=m]
    half8 qf[4];
#pragma unroll
    for (int kt = 0; kt < 4; ++kt)
        qf[kt] = *(const half8*)(q_h + qrow * DH + kt * 16 + h * 8);

    floatx16 Oc0, Oc1;   // O^T accum: d rows (2 tiles of 32), col m=c
#pragma unroll
    for (int i = 0; i < 16; ++i) { Oc0[i] = 0.f; Oc1[i] = 0.f; }
    float l4[4] = {0.f, 0.f, 0.f, 0.f};   // deferred l partials (this lane's half)
    // m_run init 8: on this data the log2-domain row max never nears 16, so
    // the defer-max branch never fires -> no rescale passes at all.
    float m_run = 8.0f;

    STAGE(0);
    __syncthreads();   // compiler drains vmcnt(0) before barrier

#pragma unroll 1
    for (int it = 0; it < NITER; ++it) {
        const int pb = it & 1;
        if (it + 1 < NITER) STAGE(pb ^ 1);   // prefetch next tile (async)

        const char* kbase = (const char*)(&k_lds[pb][0][0]);
        const char* vbase = (const char*)(&vt_lds[pb][0][0]);

        // S^T - m_run = K * Q^T + (-m_run): acc seeded with -m_run so the
        // softmax subtract comes free out of the MFMA.
        floatx16 Sc[2];
        const float negm = -m_run;
        __builtin_amdgcn_s_setprio(1);
#pragma unroll
        for (int a = 0; a < 2; ++a) {
            floatx16 acc;
#pragma unroll
            for (int i = 0; i < 16; ++i) acc[i] = negm;
#pragma unroll
            for (int kt = 0; kt < 4; ++kt) {
                half8 af = *(const half8*)(kbase + (a * 32 + c) * 128 + koff[kt]);
                acc = __builtin_amdgcn_mfma_f32_32x32x16_f16(af, qf[kt], acc, 0, 0, 0);
            }
            Sc[a] = acc;
        }
        __builtin_amdgcn_s_setprio(0);

        // guard: per-lane max3 tree over Sc (no cross-lane shfl on fast path)
        float t3[11];
#pragma unroll
        for (int i = 0; i < 10; ++i) {
            float u0 = (3 * i < 16) ? Sc[0][3 * i] : Sc[1][3 * i - 16];
            float u1 = (3 * i + 1 < 16) ? Sc[0][3 * i + 1] : Sc[1][3 * i - 15];
            float u2 = (3 * i + 2 < 16) ? Sc[0][3 * i + 2] : Sc[1][3 * i - 14];
            t3[i] = fmaxf(fmaxf(u0, u1), u2);
        }
        t3[10] = fmaxf(Sc[1][14], Sc[1][15]);
        float m0 = fmaxf(fmaxf(t3[0], t3[1]), t3[2]);
        float m1 = fmaxf(fmaxf(t3[3], t3[4]), t3[5]);
        float m2 = fmaxf(fmaxf(t3[6], t3[7]), t3[8]);
        float lmax = fmaxf(fmaxf(m0, m1), fmaxf(m2, fmaxf(t3[9], t3[10])));
        if (__any(lmax > 8.0f)) {   // never on this data
            float tt = fmaxf(lmax, __shfl_xor(lmax, 32, 64));  // exact row max
            float alpha = exp2f(-tt);
#pragma unroll
            for (int j = 0; j < 4; ++j) l4[j] *= alpha;
#pragma unroll
            for (int i = 0; i < 16; ++i) { Oc0[i] *= alpha; Oc1[i] *= alpha; }
#pragma unroll
            for (int a = 0; a < 2; ++a)
#pragma unroll
                for (int r = 0; r < 16; ++r) Sc[a][r] -= tt;
            m_run += tt;
        }
#pragma unroll
        for (int a = 0; a < 2; ++a)
#pragma unroll
            for (int r = 0; r < 16; ++r) Sc[a][r] = exp2f(Sc[a][r]);

        // P: C-layout -> B-operand frags, in-register.
#pragma unroll
        for (int a = 0; a < 2; ++a) {
            uint2 pk0 = {pkrtz(Sc[a][0],  Sc[a][1]),  pkrtz(Sc[a][2],  Sc[a][3])};
            uint2 pk1 = {pkrtz(Sc[a][4],  Sc[a][5]),  pkrtz(Sc[a][6],  Sc[a][7])};
            uint2 pk2 = {pkrtz(Sc[a][8],  Sc[a][9]),  pkrtz(Sc[a][10], Sc[a][11])};
            uint2 pk3 = {pkrtz(Sc[a][12], Sc[a][13]), pkrtz(Sc[a][14], Sc[a][15])};
            union { uint4 u; half8 f; } f0, f1;
#if __has_builtin(__builtin_amdgcn_permlane32_swap)
            {
                auto r0s = __builtin_amdgcn_permlane32_swap(pk0.x, pk1.x, false, false);
                auto r1s = __builtin_amdgcn_permlane32_swap(pk0.y, pk1.y, false, false);
                auto r2s = __builtin_amdgcn_permlane32_swap(pk2.x, pk3.x, false, false);
                auto r3s = __builtin_amdgcn_permlane32_swap(pk2.y, pk3.y, false, false);
                f0.u.x = r0s[0]; f0.u.z = r0s[1];
                f0.u.y = r1s[0]; f0.u.w = r1s[1];
                f1.u.x = r2s[0]; f1.u.z = r2s[1];
                f1.u.y = r3s[0]; f1.u.w = r3s[1];
            }
#else
            {
                uint2 s0, s1, ex0, ex1;
                s0.x = h ? pk0.x : pk1.x;  s0.y = h ? pk0.y : pk1.y;
                s1.x = h ? pk2.x : pk3.x;  s1.y = h ? pk2.y : pk3.y;
                ex0.x = __shfl_xor((int)s0.x, 32, 64);
                ex0.y = __shfl_xor((int)s0.y, 32, 64);
                ex1.x = __shfl_xor((int)s1.x, 32, 64);
                ex1.y = __shfl_xor((int)s1.y, 32, 64);
                f0.u.x = h ? ex0.x : pk0.x;  f0.u.y = h ? ex0.y : pk0.y;
                f0.u.z = h ? pk1.x : ex0.x;  f0.u.w = h ? pk1.y : ex0.y;
                f1.u.x = h ? ex1.x : pk2.x;  f1.u.y = h ? ex1.y : pk2.y;
                f1.u.z = h ? pk3.x : ex1.x;  f1.u.w = h ? pk3.y : ex1.y;
            }
#endif
            // O^T += V^T * P^T for kt = 2a, 2a+1
            __builtin_amdgcn_s_setprio(1);
#pragma unroll
            for (int bq = 0; bq < 2; ++bq) {
                int kt = 2 * a + bq;
                half8 pf = bq ? f1.f : f0.f;
                half8 vf0 = *(const half8*)(vbase + c * 128 + koff[kt]);
                half8 vf1 = *(const half8*)(vbase + (32 + c) * 128 + koff[kt]);
                Oc0 = __builtin_amdgcn_mfma_f32_32x32x16_f16(vf0, pf, Oc0, 0, 0, 0);
                Oc1 = __builtin_amdgcn_mfma_f32_32x32x16_f16(vf1, pf, Oc1, 0, 0, 0);
            }
            __builtin_amdgcn_s_setprio(0);
        }

        // deferred l accumulation: AFTER PV issue (off the critical path),
        // tree to 4 per-lane partials, no cross-lane op.
        {
            float t16v[8];
#pragma unroll
            for (int i = 0; i < 8; ++i)
                t16v[i] = (Sc[0][i] + Sc[0][i + 8]) + (Sc[1][i] + Sc[1][i + 8]);
#pragma unroll
            for (int j = 0; j < 4; ++j) l4[j] += t16v[j] + t16v[j + 4];
        }

        __syncthreads();   // drains vmcnt -> prefetched tile ready; LDS reuse safe
    }
#undef STAGE

    // epilogue: finish l, normalize, store f16 partial + (m,l)
    float lsum = (l4[0] + l4[1]) + (l4[2] + l4[3]);
    lsum += __shfl_xor(lsum, 32, 64);
    const float inv = 1.0f / lsum;
    const long obase = ((long)sp * BB * MM + (long)b * MM + mbase + c) * DH;
#pragma unroll
    for (int dt = 0; dt < 2; ++dt) {
        const floatx16& O = dt ? Oc1 : Oc0;
#pragma unroll
        for (int s2 = 0; s2 < 4; ++s2) {
            uint2 hv;
            hv.x = pkrtz(O[s2 * 4 + 0] * inv, O[s2 * 4 + 1] * inv);
            hv.y = pkrtz(O[s2 * 4 + 2] * inv, O[s2 * 4 + 3] * inv);
            *(uint2*)(Opart + obase + dt * 32 + s2 * 8 + h * 4) = hv;
        }
    }
    if (h == 0)
        ml[((long)sp * BB + b) * MM + mbase + c] = make_float2(m_run, lsum);
}

// ---------------- merge the NSP KV-split partials ----------------------------
// Opart is NORMALIZED f16; weight of split i = exp2(mi-mmax)*li.
__global__ __launch_bounds__(256) void merge_kernel(const _Float16* __restrict__ Opart,
                                                    const float2* __restrict__ ml,
                                                    float* __restrict__ out) {
    const long g8 = (long)blockIdx.x * 256 + threadIdx.x;  // 8-elem chunk
    const long row = g8 >> 3;                              // 8 chunks per row
    float2 p[NSP];
    float mmax = -INFINITY;
#pragma unroll
    for (int i = 0; i < NSP; ++i) {
        p[i] = ml[(long)i * BB * MM + row];
        mmax = fmaxf(mmax, p[i].x);
    }
    float denom = 0.f;
    float o[8] = {0.f, 0.f, 0.f, 0.f, 0.f, 0.f, 0.f, 0.f};
#pragma unroll
    for (int i = 0; i < NSP; ++i) {
        float wi = exp2f(p[i].x - mmax) * p[i].y;
        denom += wi;
        half8 v = *(const half8*)(Opart + (long)i * (BB * MM * DH) + g8 * 8);
#pragma unroll
        for (int j = 0; j < 8; ++j) o[j] += wi * (float)v[j];
    }
    float inv = 1.0f / denom;
    float4 o0 = {o[0] * inv, o[1] * inv, o[2] * inv, o[3] * inv};
    float4 o1 = {o[4] * inv, o[5] * inv, o[6] * inv, o[7] * inv};
    ((float4*)out)[g8 * 2] = o0;
    ((float4*)out)[g8 * 2 + 1] = o1;
}

extern "C" void kernel_launch(void* const* d_in, const int* in_sizes, int n_in,
                              void* d_out, int out_size, void* d_ws, size_t ws_size,
                              hipStream_t stream) {
    const float* x    = (const float*)d_in[0];
    const float* cond = (const float*)d_in[1];
    const float* Wq   = (const float*)d_in[2];
    const float* Wkv  = (const float*)d_in[3];
    float* out = (float*)d_out;

    char* ws = (char*)d_ws;
    // ws: wt 192KB | q 2MB | k 2MB | vt 2MB | Opart(f16) 8x2MB | ml 1MB ~23MB
    _Float16* wt   = (_Float16*)(ws);
    _Float16* q_h  = (_Float16*)(ws + 196608);
    _Float16* k_h  = (_Float16*)(ws + 196608 + 2097152);
    _Float16* vt_h = (_Float16*)(ws + 196608 + 2 * 2097152);
    _Float16* Op   = (_Float16*)(ws + 196608 + 3 * 2097152);
    float2*   mlp  = (float2*)(ws + 196608 + 3 * 2097152 + (size_t)NSP * 2097152);

    wtrans_kernel<<<192, 256, 0, stream>>>(Wq, Wkv, wt);
    proj_kernel<<<BB * (MM + NN) / 32, 256, 0, stream>>>(x, cond, wt, q_h, k_h, vt_h);
    fa_kernel<<<NSP * BB * 32, 256, 0, stream>>>(q_h, k_h, vt_h, Op, mlp);
    merge_kernel<<<BB * MM * DH / 8 / 256, 256, 0, stream>>>(Op, mlp, out);
}